// Round 7
// baseline (430.306 us; speedup 1.0000x reference)
//
#include <hip/hip_runtime.h>
#include <cstdint>

#define Bn 64
#define Ln 512
#define Hn 768
#define Tn 16
#define Cn 8     // chunks over L
#define Sn 64    // chunk length
#define LOG16 2.7725887222397812f

// ---------------- K1: fused logits + bias + shift, register-buffered streaming ----------
// Round-6 post-mortem: 204-load dependency soup w/ 72 VGPRs -> serialized L1 round trips
// (VALUBusy 13%).  Fix: thread (q=row, j=t) buffers BOTH operands per 32-K slice in regs
// (8 W float4 + 8 A float4 = 16 independent loads, then 32 FMAs), no LDS, no barriers.
// A loads: same address across the 16 j-lanes of a group -> HW broadcast, 4 unique
// rows/wave-inst.  W row j per lane: 48 KB total, L1-resident.  Consecutive slices
// software-pipeline.  Grid 2048 x 256 thr, launch_bounds(256,6): VGPR cap 85,
// 24 waves/CU (75% occ).  k-order per output strictly sequential (r2-r4 lineage).
__global__ __launch_bounds__(256, 6) void k_logits(
    const float* __restrict__ hs, const float* __restrict__ W,
    const float* __restrict__ bias, float* __restrict__ em) {
  int tid = threadIdx.x;
  int q = tid >> 4, j = tid & 15;
  int row = blockIdx.x * 16 + q;
  const float4* a4 = (const float4*)(hs + (size_t)row * Hn);
  const float4* w4 = (const float4*)(W + (size_t)j * Hn);
  float acc = 0.f;
#pragma unroll 1
  for (int s = 0; s < 24; ++s) {       // 24 slices x 32 K
    float4 wv[8], av[8];
#pragma unroll
    for (int m = 0; m < 8; ++m) wv[m] = w4[s * 8 + m];
#pragma unroll
    for (int m = 0; m < 8; ++m) av[m] = a4[s * 8 + m];
#pragma unroll
    for (int m = 0; m < 8; ++m) {
      acc = fmaf(av[m].x, wv[m].x, acc);
      acc = fmaf(av[m].y, wv[m].y, acc);
      acc = fmaf(av[m].z, wv[m].z, acc);
      acc = fmaf(av[m].w, wv[m].w, acc);
    }
  }
  float v = acc + bias[j];
  float mx = v;                        // per-row max over t (t == lane j within group)
  mx = fmaxf(mx, __shfl_xor(mx, 1));
  mx = fmaxf(mx, __shfl_xor(mx, 2));
  mx = fmaxf(mx, __shfl_xor(mx, 4));
  mx = fmaxf(mx, __shfl_xor(mx, 8));
  em[(size_t)row * Tn + j] = v - (mx + LOG16);   // wave writes 256B contiguous
}

// ---------------- K2: CRF numerator per batch (uses shifted em; shift cancels vs denom) --
__global__ __launch_bounds__(256) void k_numer(
    const float* __restrict__ em, const int* __restrict__ labels,
    const int* __restrict__ mask, const float* __restrict__ start,
    const float* __restrict__ endt, const float* __restrict__ trans,
    float* __restrict__ numer) {
  int b = blockIdx.x, tid = threadIdx.x;
  float s = 0.f; int msum = 0;
  for (int l = tid; l < Ln; l += 256) {
    int y = labels[b*Ln + l];
    int m = mask[b*Ln + l];
    msum += m;
    if (l == 0) {
      s += start[y] + em[((size_t)b*Ln)*Tn + y];
    } else if (m) {
      int yp = labels[b*Ln + l - 1];
      s += trans[yp*Tn + y] + em[((size_t)b*Ln + l)*Tn + y];
    }
  }
  for (int off = 32; off; off >>= 1) {
    s += __shfl_down(s, off);
    msum += __shfl_down(msum, off);
  }
  __shared__ float sw[4]; __shared__ int mw[4];
  int wid = tid >> 6, ln = tid & 63;
  if (ln == 0) { sw[wid] = s; mw[wid] = msum; }
  __syncthreads();
  if (tid == 0) {
    float st = sw[0]+sw[1]+sw[2]+sw[3];
    int mt = mw[0]+mw[1]+mw[2]+mw[3];
    int last = labels[b*Ln + mt - 1];
    numer[b] = st + endt[last];
  }
}

// ---------------- K3: denominator chunk matrices (linear-space matrix product chain) ----
__global__ __launch_bounds__(256) void k_denom_chunk(
    const float* __restrict__ em, const int* __restrict__ mask,
    const float* __restrict__ trans, float* __restrict__ qmat) {
  int bc = blockIdx.x, b = bc >> 3, c = bc & 7;
  int tid = threadIdx.x, i = tid >> 4, tp = tid & 15;
  int l0 = c * Sn;
  __shared__ float ems[Sn * Tn];
  __shared__ int msk[Sn];
  const float* src = em + ((size_t)b*Ln + l0)*Tn;
  for (int k = tid; k < Sn*Tn; k += 256) ems[k] = src[k];
  if (tid < Sn) msk[tid] = mask[b*Ln + l0 + tid];
  float etr[Tn];
#pragma unroll
  for (int t = 0; t < Tn; ++t) etr[t] = __expf(trans[t*Tn + tp]);
  __syncthreads();
  float p = (tp == i) ? 1.f : 0.f;   // identity row i
  float logs = 0.f;
  int lstart = (c == 0) ? 1 : l0;
  for (int l = lstart; l < l0 + Sn; ++l) {
    float cs = __expf(ems[(l - l0)*Tn + tp]);
    float dot = 0.f;
#pragma unroll
    for (int t = 0; t < Tn; ++t) dot = fmaf(__shfl(p, t, 16), etr[t], dot);
    float pn = dot * cs;
    p = msk[l - l0] ? pn : p;
    if ((l & 15) == 15) {            // per-row renorm; last trigger is the final step
      float m = p;
      m = fmaxf(m, __shfl_xor(m, 1));
      m = fmaxf(m, __shfl_xor(m, 2));
      m = fmaxf(m, __shfl_xor(m, 4));
      m = fmaxf(m, __shfl_xor(m, 8));
      p /= m;
      logs += __logf(m);
    }
  }
  qmat[(((size_t)b*Cn + c)*Tn + i)*Tn + tp] = __logf(p) + logs;
}

// ---------------- K5: Viterbi chunk matrices + per-chunk argmax history -----------------
__global__ __launch_bounds__(256) void k_vit_chunk(
    const float* __restrict__ em, const float* __restrict__ trans,
    float* __restrict__ qv, uint8_t* __restrict__ hist) {
  int bc = blockIdx.x, b = bc >> 3, c = bc & 7;
  int tid = threadIdx.x, i = tid >> 4, tp = tid & 15;
  int l0 = c * Sn;
  __shared__ float ems[Sn * Tn];
  __shared__ uint8_t hl[Tn * Sn * Tn];    // [i][l'][t'] 16KB
  const float* src = em + ((size_t)b*Ln + l0)*Tn;
  for (int k = tid; k < Sn*Tn; k += 256) ems[k] = src[k];
  float tcol[Tn];
#pragma unroll
  for (int t = 0; t < Tn; ++t) tcol[t] = trans[t*Tn + tp];
  __syncthreads();
  float v = (tp == i) ? 0.f : -1e30f;     // max-plus identity row i
  int lstart = (c == 0) ? 1 : l0;
  for (int l = lstart; l < l0 + Sn; ++l) {
    float best = -3.0e38f; int arg = 0;
#pragma unroll
    for (int t = 0; t < Tn; ++t) {        // strict > keeps FIRST max (jnp.argmax semantics)
      float cand = __shfl(v, t, 16) + tcol[t];
      bool g = cand > best;
      arg = g ? t : arg;
      best = g ? cand : best;
    }
    v = best + ems[(l - l0)*Tn + tp];
    hl[(i*Sn + (l - l0))*Tn + tp] = (uint8_t)arg;
  }
  qv[(((size_t)b*Cn + c)*Tn + i)*Tn + tp] = v;
  __syncthreads();
  const uint4* s4 = (const uint4*)hl;     // coalesced 16KB dump
  uint4* d4 = (uint4*)(hist + (size_t)bc * (Tn*Sn*Tn));
  for (int k = tid; k < (Tn*Sn*Tn)/16; k += 256) d4[k] = s4[k];
}

// ---------------- K4: fold denominator chunks (log-space), compute loss -----------------
__global__ __launch_bounds__(1024) void k_loss(
    const float* __restrict__ qmat, const float* __restrict__ em,
    const float* __restrict__ start, const float* __restrict__ endt,
    const float* __restrict__ numer, float* __restrict__ out) {
  int tid = threadIdx.x, b = tid >> 4, k = tid & 15;   // 64 batches x 16 lanes
  float p = start[k] + em[((size_t)b*Ln)*Tn + k];
  for (int c = 0; c < Cn; ++c) {
    float vals[Tn]; float mx = -3.0e38f;
#pragma unroll
    for (int i = 0; i < Tn; ++i) {
      float cand = __shfl(p, i, 16) + qmat[(((size_t)b*Cn + c)*Tn + i)*Tn + k];
      vals[i] = cand;
      mx = fmaxf(mx, cand);
    }
    float sm = 0.f;
#pragma unroll
    for (int i = 0; i < Tn; ++i) sm += __expf(vals[i] - mx);
    p = mx + __logf(sm);
  }
  float x = p + endt[k];
  float mx = x;
  mx = fmaxf(mx, __shfl_xor(mx, 1));
  mx = fmaxf(mx, __shfl_xor(mx, 2));
  mx = fmaxf(mx, __shfl_xor(mx, 4));
  mx = fmaxf(mx, __shfl_xor(mx, 8));
  float e = __expf(x - mx);
  e += __shfl_xor(e, 1);
  e += __shfl_xor(e, 2);
  e += __shfl_xor(e, 4);
  e += __shfl_xor(e, 8);
  float denom = mx + __logf(e);
  __shared__ float red[Bn];
  if (k == 0) red[b] = numer[b] - denom;
  __syncthreads();
  if (tid < 64) {
    float vv = red[tid];
    for (int off = 32; off; off >>= 1) vv += __shfl_down(vv, off);
    if (tid == 0) out[0] = -vv * (1.0f / Bn);
  }
}

// ---------------- K6: Viterbi fold + parallel per-chunk backtrack -----------------------
__global__ __launch_bounds__(512) void k_vit_bt(
    const float* __restrict__ qv, const float* __restrict__ em,
    const float* __restrict__ start, const float* __restrict__ endt,
    const uint8_t* __restrict__ hist, float* __restrict__ tags) {
  int b = blockIdx.x, tid = threadIdx.x;
  __shared__ int Bs[Cn][Tn];
  __shared__ int bnd[Cn + 1];
  if (tid < Tn) {
    int k = tid;
    float p = start[k] + em[((size_t)b*Ln)*Tn + k];
    for (int c = 0; c < Cn; ++c) {
      float best = -3.0e38f; int arg = 0;
#pragma unroll
      for (int i = 0; i < Tn; ++i) {
        float cand = __shfl(p, i, 16) + qv[(((size_t)b*Cn + c)*Tn + i)*Tn + k];
        bool g = cand > best;
        arg = g ? i : arg;
        best = g ? cand : best;
      }
      Bs[c][k] = arg;
      p = best;
    }
    float x = p + endt[k]; int idx = k;   // first-max argmax over k
#pragma unroll
    for (int d = 1; d < 16; d <<= 1) {
      float xo = __shfl_xor(x, d);
      int io = __shfl_xor(idx, d);
      bool take = (xo > x) || (xo == x && io < idx);
      x = take ? xo : x;
      idx = take ? io : idx;
    }
    if (k == 0) bnd[Cn] = idx;
  }
  __syncthreads();
  if (tid == 0) {                         // boundary states via fold backpointers
    int t = bnd[Cn];
    for (int c = Cn - 1; c >= 0; --c) { t = Bs[c][t]; bnd[c] = t; }
  }
  __syncthreads();
  int w = tid >> 6, lane = tid & 63;      // wave w backtracks chunk w
  int istar = bnd[w];
  int cur = bnd[w + 1];
  int l0 = w * Sn;
  const uint4* hp = (const uint4*)(hist + ((size_t)(b*Cn + w)*Tn + istar)*(Sn*Tn));
  uint4 hh = hp[lane];                    // lane l' holds hist bytes for step l0+l'
  float mytag = (lane == 63) ? (float)cur : 0.f;
  for (int l = l0 + 63; l >= l0 + 1; --l) {
    int sl = l - l0;
    unsigned w0 = __shfl((int)hh.x, sl);
    unsigned w1 = __shfl((int)hh.y, sl);
    unsigned w2 = __shfl((int)hh.z, sl);
    unsigned w3 = __shfl((int)hh.w, sl);
    unsigned word = (cur < 8) ? ((cur < 4) ? w0 : w1) : ((cur < 12) ? w2 : w3);
    cur = (int)((word >> ((cur & 3) * 8)) & 0xff);
    if (lane == sl - 1) mytag = (float)cur;
  }
  tags[(size_t)b*Ln + l0 + lane] = mytag; // coalesced
}

extern "C" void kernel_launch(void* const* d_in, const int* in_sizes, int n_in,
                              void* d_out, int out_size, void* d_ws, size_t ws_size,
                              hipStream_t stream) {
  const float* hs     = (const float*)d_in[0];
  const int*   mask   = (const int*)d_in[1];
  const int*   labels = (const int*)d_in[2];
  const float* W      = (const float*)d_in[3];
  const float* bias   = (const float*)d_in[4];
  const float* start  = (const float*)d_in[5];
  const float* endt   = (const float*)d_in[6];
  const float* trans  = (const float*)d_in[7];
  float* out = (float*)d_out;

  // Workspace layout (~11.5 MB):
  //   em    @ 0        : 64*512*16*4 = 2,097,152 B
  //   qmat  @ 2 MB     : 64*8*16*16*4 =  524,288 B
  //   qv    @ 2.5 MB   :                 524,288 B
  //   numer @ 3 MB     :                     256 B (padded to 4 KB)
  //   hist  @ 3 MB+4KB : 64*8*16*64*16 = 8,388,608 B
  char* ws = (char*)d_ws;
  float*   em    = (float*)(ws);
  float*   qmat  = (float*)(ws + (size_t)(1u<<21));
  float*   qv    = (float*)(ws + (size_t)(1u<<21) + 524288);
  float*   numer = (float*)(ws + (size_t)(1u<<21) + 1048576);
  uint8_t* hist  = (uint8_t*)(ws + (size_t)(1u<<21) + 1048576 + 4096);

  hipLaunchKernelGGL(k_logits,      dim3(2048), dim3(256), 0, stream, hs, W, bias, em);
  hipLaunchKernelGGL(k_numer,       dim3(64),   dim3(256), 0, stream, em, labels, mask, start, endt, trans, numer);
  hipLaunchKernelGGL(k_denom_chunk, dim3(512),  dim3(256), 0, stream, em, mask, trans, qmat);
  hipLaunchKernelGGL(k_vit_chunk,   dim3(512),  dim3(256), 0, stream, em, trans, qv, hist);
  hipLaunchKernelGGL(k_loss,        dim3(1),    dim3(1024),0, stream, qmat, em, start, endt, numer, out);
  hipLaunchKernelGGL(k_vit_bt,      dim3(64),   dim3(512), 0, stream, qv, em, start, endt, hist, out + 1);
}

// Round 8
// 279.079 us; speedup vs baseline: 1.5419x; 1.5419x over previous
//
#include <hip/hip_runtime.h>
#include <cstdint>

#define Bn 64
#define Ln 512
#define Hn 768
#define Tn 16
#define Cn 8      // chunks over L
#define Sn 64     // chunk length
#define Kn 4      // K-split for GEMM
#define Kc 192    // K-slice per GEMM block (768/4)
#define Mrows (Bn*Ln)   // 32768
#define LOG16 2.7725887222397812f

// ---------------- K_A: partial GEMM, split-K, r4 structure @ 128 rows ----------------
// r4 (the best GEMM: 71us, Occ 39%, VALU 30%) reverted; deltas: Kn=4 halves partial
// traffic, 128-row blocks with wave-level t-split keep W wave-uniform (s_load, as r4).
// k-accumulation order identical to r2-r5 lineage -> em BIT-IDENTICAL -> tags unchanged.
__global__ __launch_bounds__(256) void k_gemm_part(
    const float* __restrict__ hs, const float* __restrict__ W,
    float* __restrict__ partial) {
  int bx = blockIdx.x;
  int rt = bx >> 2, s = bx & 3;
  int tid = threadIdx.x;
  int r0 = rt * 128, kb = s * Kc;
  int row = (tid & 63) + ((tid >> 7) << 6);   // waves 0,1 -> rows 0-63; waves 2,3 -> 64-127
  int t0 = ((tid >> 6) & 1) * 8;              // wave-uniform t-half -> W via s_load
  __shared__ float alds[128 * 36];            // 18,432 B; stride 36 as r4 (0 conflicts meas.)
  float acc[8] = {0.f};
#pragma unroll 1
  for (int cc = 0; cc < 6; ++cc) {            // 6 sub-chunks of 32 K-floats
    int k0 = kb + cc * 32;
#pragma unroll
    for (int it = 0; it < 4; ++it) {          // 1024 float4: 128 rows x 8 slots
      int f = it * 256 + tid;
      int r = f >> 3, j = f & 7;              // 128B contiguous run per row
      float4 v = *(const float4*)(hs + (size_t)(r0 + r) * Hn + k0 + j * 4);
      *(float4*)&alds[r * 36 + j * 4] = v;
    }
    __syncthreads();
#pragma unroll
    for (int j = 0; j < 8; ++j) {
      float4 a = *(const float4*)&alds[row * 36 + j * 4];
#pragma unroll
      for (int tt = 0; tt < 8; ++tt) {
        const float* w = W + (t0 + tt) * Hn + k0 + j * 4;   // wave-uniform -> s_load
        acc[tt] = fmaf(a.x, w[0], fmaf(a.y, w[1], fmaf(a.z, w[2], fmaf(a.w, w[3], acc[tt]))));
      }
    }
    __syncthreads();
  }
  float* dst = partial + ((size_t)s * Mrows + (r0 + row)) * Tn + t0;
  *(float4*)(dst + 0) = make_float4(acc[0], acc[1], acc[2], acc[3]);
  *(float4*)(dst + 4) = make_float4(acc[4], acc[5], acc[6], acc[7]);
}

// ---------------- K_B: fused reduce+em+denom-scan+vit-scan, block = (b,chunk) ----------
// Tail fusion: the chunk (b,c) needs exactly rows bc*64..+63 of em -> compute em here
// (from partial), keep in LDS, run BOTH scans.  Kills k_reduce/k_denom/k_vit launches
// and the em reload.  partial (read) and hist (write) are now concurrently live ->
// disjoint ws regions (no aliasing).
__global__ __launch_bounds__(256) void k_em_scan(
    const float* __restrict__ partial, const float* __restrict__ bias,
    const int* __restrict__ mask, const float* __restrict__ trans,
    float* __restrict__ em, float* __restrict__ qmat,
    float* __restrict__ qv, uint8_t* __restrict__ hist) {
  int bc = blockIdx.x, b = bc >> 3, c = bc & 7;
  int tid = threadIdx.x, i = tid >> 4, tp = tid & 15;
  int l0 = c * Sn;
  __shared__ float ems[Sn * Tn];
  __shared__ int msk[Sn];
  __shared__ uint8_t hl[Tn * Sn * Tn];   // 16 KB
  // phase 0: reduce partial -> em (bit-identical order to r4 reduce: bias + s0..s3)
#pragma unroll
  for (int g = 0; g < 4; ++g) {
    int rl = (tid >> 4) + g * 16, t = tid & 15;
    int grow = bc * Sn + rl;
    float sum = bias[t];
#pragma unroll
    for (int s = 0; s < Kn; ++s) sum += partial[((size_t)s * Mrows + grow) * Tn + t];
    float mx = sum;
    mx = fmaxf(mx, __shfl_xor(mx, 1));
    mx = fmaxf(mx, __shfl_xor(mx, 2));
    mx = fmaxf(mx, __shfl_xor(mx, 4));
    mx = fmaxf(mx, __shfl_xor(mx, 8));
    float ev = sum - (mx + LOG16);
    ems[rl * Tn + t] = ev;
    em[(size_t)grow * Tn + t] = ev;
  }
  if (tid < Sn) msk[tid] = mask[b * Ln + l0 + tid];
  float etr[Tn], tcol[Tn];
#pragma unroll
  for (int t = 0; t < Tn; ++t) {
    float tv = trans[t * Tn + tp];
    etr[t] = __expf(tv);
    tcol[t] = tv;
  }
  __syncthreads();
  int lstart = (c == 0) ? 1 : l0;
  // phase 1: denominator scan (linear space, renorm every 16)
  {
    float p = (tp == i) ? 1.f : 0.f;
    float logs = 0.f;
    for (int l = lstart; l < l0 + Sn; ++l) {
      float cs = __expf(ems[(l - l0) * Tn + tp]);
      float dot = 0.f;
#pragma unroll
      for (int t = 0; t < Tn; ++t) dot = fmaf(__shfl(p, t, 16), etr[t], dot);
      float pn = dot * cs;
      p = msk[l - l0] ? pn : p;
      if ((l & 15) == 15) {
        float m = p;
        m = fmaxf(m, __shfl_xor(m, 1));
        m = fmaxf(m, __shfl_xor(m, 2));
        m = fmaxf(m, __shfl_xor(m, 4));
        m = fmaxf(m, __shfl_xor(m, 8));
        p /= m;
        logs += __logf(m);
      }
    }
    qmat[(((size_t)b * Cn + c) * Tn + i) * Tn + tp] = __logf(p) + logs;
  }
  // phase 2: Viterbi scan (max-plus) + history
  {
    float v = (tp == i) ? 0.f : -1e30f;
    for (int l = lstart; l < l0 + Sn; ++l) {
      float best = -3.0e38f; int arg = 0;
#pragma unroll
      for (int t = 0; t < Tn; ++t) {      // strict > keeps FIRST max (jnp.argmax)
        float cand = __shfl(v, t, 16) + tcol[t];
        bool g = cand > best;
        arg = g ? t : arg;
        best = g ? cand : best;
      }
      v = best + ems[(l - l0) * Tn + tp];
      hl[(i * Sn + (l - l0)) * Tn + tp] = (uint8_t)arg;
    }
    qv[(((size_t)b * Cn + c) * Tn + i) * Tn + tp] = v;
  }
  __syncthreads();
  const uint4* s4 = (const uint4*)hl;     // coalesced 16KB dump
  uint4* d4 = (uint4*)(hist + (size_t)bc * (Tn * Sn * Tn));
  for (int k = tid; k < (Tn * Sn * Tn) / 16; k += 256) d4[k] = s4[k];
}

// ---------------- K_C: numerator + denominator fold -> llh[b] ----------------
__global__ __launch_bounds__(256) void k_numer_loss(
    const float* __restrict__ em, const int* __restrict__ labels,
    const int* __restrict__ mask, const float* __restrict__ start,
    const float* __restrict__ endt, const float* __restrict__ trans,
    const float* __restrict__ qmat, float* __restrict__ llh) {
  int b = blockIdx.x, tid = threadIdx.x;
  float s = 0.f; int msum = 0;
  for (int l = tid; l < Ln; l += 256) {
    int y = labels[b * Ln + l];
    int m = mask[b * Ln + l];
    msum += m;
    if (l == 0) {
      s += start[y] + em[((size_t)b * Ln) * Tn + y];
    } else if (m) {
      int yp = labels[b * Ln + l - 1];
      s += trans[yp * Tn + y] + em[((size_t)b * Ln + l) * Tn + y];
    }
  }
  for (int off = 32; off; off >>= 1) {
    s += __shfl_down(s, off);
    msum += __shfl_down(msum, off);
  }
  __shared__ float sw[4]; __shared__ int mw[4];
  __shared__ float snum;
  int wid = tid >> 6, ln = tid & 63;
  if (ln == 0) { sw[wid] = s; mw[wid] = msum; }
  __syncthreads();
  if (tid == 0) {
    float st = sw[0] + sw[1] + sw[2] + sw[3];
    int mt = mw[0] + mw[1] + mw[2] + mw[3];
    int last = labels[b * Ln + mt - 1];
    snum = st + endt[last];
  }
  __syncthreads();
  if (tid < Tn) {                         // 16-lane log-space fold over chunk matrices
    int k = tid;
    float p = start[k] + em[((size_t)b * Ln) * Tn + k];
    for (int c = 0; c < Cn; ++c) {
      float vals[Tn]; float mx = -3.0e38f;
#pragma unroll
      for (int i = 0; i < Tn; ++i) {
        float cand = __shfl(p, i, 16) + qmat[(((size_t)b * Cn + c) * Tn + i) * Tn + k];
        vals[i] = cand;
        mx = fmaxf(mx, cand);
      }
      float sm = 0.f;
#pragma unroll
      for (int i = 0; i < Tn; ++i) sm += __expf(vals[i] - mx);
      p = mx + __logf(sm);
    }
    float x = p + endt[k];
    float mx = x;
    mx = fmaxf(mx, __shfl_xor(mx, 1));
    mx = fmaxf(mx, __shfl_xor(mx, 2));
    mx = fmaxf(mx, __shfl_xor(mx, 4));
    mx = fmaxf(mx, __shfl_xor(mx, 8));
    float e = __expf(x - mx);
    e += __shfl_xor(e, 1);
    e += __shfl_xor(e, 2);
    e += __shfl_xor(e, 4);
    e += __shfl_xor(e, 8);
    float denom = mx + __logf(e);
    if (k == 0) llh[b] = snum - denom;
  }
}

// ---------------- K_D: Viterbi fold + parallel backtrack + loss finalize ----------------
__global__ __launch_bounds__(512) void k_vit_bt(
    const float* __restrict__ qv, const float* __restrict__ em,
    const float* __restrict__ start, const float* __restrict__ endt,
    const uint8_t* __restrict__ hist, const float* __restrict__ llh,
    float* __restrict__ loss_out, float* __restrict__ tags) {
  int b = blockIdx.x, tid = threadIdx.x;
  __shared__ int Bs[Cn][Tn];
  __shared__ int bnd[Cn + 1];
  if (tid < Tn) {
    int k = tid;
    float p = start[k] + em[((size_t)b * Ln) * Tn + k];
    for (int c = 0; c < Cn; ++c) {
      float best = -3.0e38f; int arg = 0;
#pragma unroll
      for (int i = 0; i < Tn; ++i) {
        float cand = __shfl(p, i, 16) + qv[(((size_t)b * Cn + c) * Tn + i) * Tn + k];
        bool g = cand > best;
        arg = g ? i : arg;
        best = g ? cand : best;
      }
      Bs[c][k] = arg;
      p = best;
    }
    float x = p + endt[k]; int idx = k;   // first-max argmax over k
#pragma unroll
    for (int d = 1; d < 16; d <<= 1) {
      float xo = __shfl_xor(x, d);
      int io = __shfl_xor(idx, d);
      bool take = (xo > x) || (xo == x && io < idx);
      x = take ? xo : x;
      idx = take ? io : idx;
    }
    if (k == 0) bnd[Cn] = idx;
  }
  __syncthreads();
  if (tid == 0) {
    int t = bnd[Cn];
    for (int c = Cn - 1; c >= 0; --c) { t = Bs[c][t]; bnd[c] = t; }
  }
  __syncthreads();
  int w = tid >> 6, lane = tid & 63;      // wave w backtracks chunk w
  int istar = bnd[w];
  int cur = bnd[w + 1];
  int l0 = w * Sn;
  const uint4* hp = (const uint4*)(hist + ((size_t)(b * Cn + w) * Tn + istar) * (Sn * Tn));
  uint4 hh = hp[lane];
  float mytag = (lane == 63) ? (float)cur : 0.f;
  for (int l = l0 + 63; l >= l0 + 1; --l) {
    int sl = l - l0;
    unsigned w0 = __shfl((int)hh.x, sl);
    unsigned w1 = __shfl((int)hh.y, sl);
    unsigned w2 = __shfl((int)hh.z, sl);
    unsigned w3 = __shfl((int)hh.w, sl);
    unsigned word = (cur < 8) ? ((cur < 4) ? w0 : w1) : ((cur < 12) ? w2 : w3);
    cur = (int)((word >> ((cur & 3) * 8)) & 0xff);
    if (lane == sl - 1) mytag = (float)cur;
  }
  tags[(size_t)b * Ln + l0 + lane] = mytag;
  if (b == 0 && tid < Bn) {               // loss finalize (llh written by K_C)
    float vv = llh[tid];
    for (int off = 32; off; off >>= 1) vv += __shfl_down(vv, off);
    if (tid == 0) loss_out[0] = -vv * (1.0f / Bn);
  }
}

extern "C" void kernel_launch(void* const* d_in, const int* in_sizes, int n_in,
                              void* d_out, int out_size, void* d_ws, size_t ws_size,
                              hipStream_t stream) {
  const float* hs     = (const float*)d_in[0];
  const int*   mask   = (const int*)d_in[1];
  const int*   labels = (const int*)d_in[2];
  const float* W      = (const float*)d_in[3];
  const float* bias   = (const float*)d_in[4];
  const float* start  = (const float*)d_in[5];
  const float* endt   = (const float*)d_in[6];
  const float* trans  = (const float*)d_in[7];
  float* out = (float*)d_out;

  // Workspace (~19.0 MB, NO aliasing — partial & hist are concurrently live in K_B):
  //   em      @ 0          : 2,097,152
  //   qmat    @ 2,097,152  :   524,288
  //   qv      @ 2,621,440  :   524,288
  //   llh     @ 3,145,728  :     4,096
  //   partial @ 3,149,824  : 8,388,608  (4*32768*16*4)
  //   hist    @ 11,538,432 : 8,388,608
  char* ws = (char*)d_ws;
  float*   em      = (float*)(ws);
  float*   qmat    = (float*)(ws + 2097152);
  float*   qv      = (float*)(ws + 2621440);
  float*   llh     = (float*)(ws + 3145728);
  float*   partial = (float*)(ws + 3149824);
  uint8_t* hist    = (uint8_t*)(ws + 11538432);

  hipLaunchKernelGGL(k_gemm_part,  dim3(1024), dim3(256), 0, stream, hs, W, partial);
  hipLaunchKernelGGL(k_em_scan,    dim3(512),  dim3(256), 0, stream, partial, bias, mask, trans, em, qmat, qv, hist);
  hipLaunchKernelGGL(k_numer_loss, dim3(64),   dim3(256), 0, stream, em, labels, mask, start, endt, trans, qmat, llh);
  hipLaunchKernelGGL(k_vit_bt,     dim3(64),   dim3(512), 0, stream, qv, em, start, endt, hist, llh, out, out + 1);
}